// Round 2
// baseline (143.407 us; speedup 1.0000x reference)
//
#include <hip/hip_runtime.h>

#define B_DIM 64
#define N_IN 1000000
#define N_OUT 20000
#define KMAX 64

// ---------- transpose src(64, C) -> dst(C, 64), 64x64 LDS tiles ----------
__global__ __launch_bounds__(256) void transpose_64xC(
    const float* __restrict__ src, float* __restrict__ dst, int C) {
    __shared__ float lds[64 * 65];
    const int c0 = blockIdx.x * 64;
    const int t  = threadIdx.x;
    const int cq = t & 63;   // 0..63
    const int rq = t >> 6;   // 0..3
#pragma unroll
    for (int i = 0; i < 16; ++i) {
        int r = i * 4 + rq;
        int c = c0 + cq;
        if (c < C) lds[r * 65 + cq] = src[r * C + c];   // coalesced read
    }
    __syncthreads();
#pragma unroll
    for (int i = 0; i < 16; ++i) {
        int c = i * 4 + rq;       // tile col
        int r = cq;               // 0..63
        if (c0 + c < C) dst[(c0 + c) * 64 + r] = lds[r * 65 + c]; // coalesced write, stride-65 LDS read (conflict-free)
    }
}

// ---------- transpose src(C, 64) -> dst(64, C) ----------
__global__ __launch_bounds__(256) void transpose_Cx64(
    const float* __restrict__ src, float* __restrict__ dst, int C) {
    __shared__ float lds[64 * 65];
    const int r0 = blockIdx.x * 64;
    const int t  = threadIdx.x;
    const int cq = t & 63;
    const int rq = t >> 6;
#pragma unroll
    for (int i = 0; i < 16; ++i) {
        int rr = i * 4 + rq;
        if (r0 + rr < C) lds[rr * 65 + cq] = src[(r0 + rr) * 64 + cq]; // coalesced read
    }
    __syncthreads();
#pragma unroll
    for (int i = 0; i < 16; ++i) {
        int c  = i * 4 + rq;      // dst row 0..63
        int rr = cq;
        if (r0 + rr < C) dst[c * C + r0 + rr] = lds[rr * 65 + c];      // coalesced write
    }
}

// ---------- gather + masked dot: one wave per group, lane = batch ----------
__global__ __launch_bounds__(256) void gather_dot(
    const float* __restrict__ xT,      // (N_IN, 64)
    const float* __restrict__ wT,      // (N_OUT, 64)
    const int*   __restrict__ gidx,    // (N_OUT, KMAX)
    const int*   __restrict__ lengths, // (N_OUT,)
    const float* __restrict__ bias,    // (N_OUT,)
    float*       __restrict__ outT) {  // (N_OUT, 64)
    const int wave = threadIdx.x >> 6;
    const int lane = threadIdx.x & 63;
    const int g = blockIdx.x * 4 + wave;
    if (g >= N_OUT) return;

    const int len = lengths[g];
    // Prefetch all 64 indices + weights coalesced; zero weights past len.
    const int   idx_l = gidx[g * KMAX + lane];
    const float w_l   = (lane < len) ? wT[g * KMAX + lane] : 0.0f;

    float acc = 0.0f;
    for (int k = 0; k < len; k += 4) {
        // indices are always valid (randint over [0,N_IN)), weights are 0 past len
        int   i0 = __shfl(idx_l, k + 0);
        int   i1 = __shfl(idx_l, k + 1);
        int   i2 = __shfl(idx_l, k + 2);
        int   i3 = __shfl(idx_l, k + 3);
        float w0 = __shfl(w_l, k + 0);
        float w1 = __shfl(w_l, k + 1);
        float w2 = __shfl(w_l, k + 2);
        float w3 = __shfl(w_l, k + 3);
        // 4 independent 256B coalesced loads in flight
        float v0 = xT[i0 * 64 + lane];
        float v1 = xT[i1 * 64 + lane];
        float v2 = xT[i2 * 64 + lane];
        float v3 = xT[i3 * 64 + lane];
        acc = fmaf(v0, w0, acc);
        acc = fmaf(v1, w1, acc);
        acc = fmaf(v2, w2, acc);
        acc = fmaf(v3, w3, acc);
    }
    outT[g * 64 + lane] = acc + bias[g];
}

// ---------- fallback (ws too small): direct, slow but correct ----------
__global__ __launch_bounds__(256) void direct_kernel(
    const float* __restrict__ x, const float* __restrict__ kern,
    const float* __restrict__ bias, const int* __restrict__ gidx,
    const int* __restrict__ lengths, float* __restrict__ out) {
    const int wave = threadIdx.x >> 6;
    const int lane = threadIdx.x & 63;   // batch
    const int g = blockIdx.x * 4 + wave;
    if (g >= N_OUT) return;
    const int len = lengths[g];
    float acc = 0.0f;
    for (int k = 0; k < len; ++k) {
        int   idx = gidx[g * KMAX + k];
        float w   = kern[k * N_OUT + g];
        acc = fmaf(x[lane * N_IN + idx], w, acc);
    }
    out[lane * N_OUT + g] = acc + bias[g];
}

extern "C" void kernel_launch(void* const* d_in, const int* in_sizes, int n_in,
                              void* d_out, int out_size, void* d_ws, size_t ws_size,
                              hipStream_t stream) {
    const float* x       = (const float*)d_in[0];
    const float* kern    = (const float*)d_in[1];
    const float* bias    = (const float*)d_in[2];
    const int*   gidx    = (const int*)d_in[3];
    const int*   lengths = (const int*)d_in[4];
    float*       out     = (float*)d_out;

    const size_t xT_bytes = (size_t)N_IN * B_DIM * sizeof(float);   // 256 MB
    const size_t wT_bytes = (size_t)N_OUT * KMAX * sizeof(float);   // 5.12 MB
    const size_t oT_bytes = (size_t)N_OUT * B_DIM * sizeof(float);  // 5.12 MB

    if (ws_size >= xT_bytes + wT_bytes + oT_bytes) {
        float* xT = (float*)d_ws;
        float* wT = (float*)((char*)d_ws + xT_bytes);
        float* oT = (float*)((char*)d_ws + xT_bytes + wT_bytes);

        transpose_64xC<<<N_IN / 64, 256, 0, stream>>>(x, xT, N_IN);
        transpose_64xC<<<(N_OUT + 63) / 64, 256, 0, stream>>>(kern, wT, N_OUT);
        gather_dot<<<N_OUT / 4, 256, 0, stream>>>(xT, wT, gidx, lengths, bias, oT);
        transpose_Cx64<<<(N_OUT + 63) / 64, 256, 0, stream>>>(oT, out, N_OUT);
    } else {
        direct_kernel<<<N_OUT / 4, 256, 0, stream>>>(x, kern, bias, gidx, lengths, out);
    }
}

// Round 3
// 112.938 us; speedup vs baseline: 1.2698x; 1.2698x over previous
//
#include <hip/hip_runtime.h>
#include <hip/hip_bf16.h>

#define B_DIM 64
#define N_IN 1000000
#define N_OUT 20000
#define KMAX 64

// ---------- transpose + downcast: src f32 (64, C) -> dst bf16 (C, 64) ----------
__global__ __launch_bounds__(256) void transpose_64xC_bf16(
    const float* __restrict__ src, __hip_bfloat16* __restrict__ dst, int C) {
    __shared__ float lds[64 * 65];
    const int c0 = blockIdx.x * 64;
    const int t  = threadIdx.x;
    const int cq = t & 63;   // 0..63
    const int rq = t >> 6;   // 0..3
#pragma unroll
    for (int i = 0; i < 16; ++i) {
        int r = i * 4 + rq;
        int c = c0 + cq;
        if (c < C) lds[r * 65 + cq] = src[r * C + c];   // coalesced 256B read
    }
    __syncthreads();
#pragma unroll
    for (int i = 0; i < 16; ++i) {
        int c = i * 4 + rq;       // tile col
        int r = cq;               // 0..63
        if (c0 + c < C)
            dst[(size_t)(c0 + c) * 64 + r] = __float2bfloat16(lds[r * 65 + c]); // coalesced 128B write
    }
}

// ---------- transpose f32: src(64, C) -> dst(C, 64) (for the small kernel matrix) ----------
__global__ __launch_bounds__(256) void transpose_64xC_f32(
    const float* __restrict__ src, float* __restrict__ dst, int C) {
    __shared__ float lds[64 * 65];
    const int c0 = blockIdx.x * 64;
    const int t  = threadIdx.x;
    const int cq = t & 63;
    const int rq = t >> 6;
#pragma unroll
    for (int i = 0; i < 16; ++i) {
        int r = i * 4 + rq;
        int c = c0 + cq;
        if (c < C) lds[r * 65 + cq] = src[r * C + c];
    }
    __syncthreads();
#pragma unroll
    for (int i = 0; i < 16; ++i) {
        int c = i * 4 + rq;
        int r = cq;
        if (c0 + c < C) dst[(c0 + c) * 64 + r] = lds[r * 65 + c];
    }
}

// ---------- transpose src(C, 64) -> dst(64, C) ----------
__global__ __launch_bounds__(256) void transpose_Cx64(
    const float* __restrict__ src, float* __restrict__ dst, int C) {
    __shared__ float lds[64 * 65];
    const int r0 = blockIdx.x * 64;
    const int t  = threadIdx.x;
    const int cq = t & 63;
    const int rq = t >> 6;
#pragma unroll
    for (int i = 0; i < 16; ++i) {
        int rr = i * 4 + rq;
        if (r0 + rr < C) lds[rr * 65 + cq] = src[(r0 + rr) * 64 + cq]; // coalesced read
    }
    __syncthreads();
#pragma unroll
    for (int i = 0; i < 16; ++i) {
        int c  = i * 4 + rq;      // dst row 0..63
        int rr = cq;
        if (r0 + rr < C) dst[c * C + r0 + rr] = lds[rr * 65 + c];      // coalesced write
    }
}

// ---------- gather + masked dot: one wave per group, lane = batch ----------
__global__ __launch_bounds__(256) void gather_dot(
    const __hip_bfloat16* __restrict__ xT, // (N_IN, 64) bf16
    const float* __restrict__ wT,          // (N_OUT, 64)
    const int*   __restrict__ gidx,        // (N_OUT, KMAX)
    const int*   __restrict__ lengths,     // (N_OUT,)
    const float* __restrict__ bias,        // (N_OUT,)
    float*       __restrict__ outT) {      // (N_OUT, 64)
    const int wave = threadIdx.x >> 6;
    const int lane = threadIdx.x & 63;
    const int g = blockIdx.x * 4 + wave;
    if (g >= N_OUT) return;

    const int len = lengths[g];
    // Prefetch all 64 indices + weights coalesced; zero weights past len.
    const int   idx_l = gidx[g * KMAX + lane];
    const float w_l   = (lane < len) ? wT[g * KMAX + lane] : 0.0f;

    float acc = 0.0f;
    for (int k = 0; k < len; k += 4) {
        // indices are always valid (randint over [0,N_IN)); weights are 0 past len
        int   i0 = __shfl(idx_l, k + 0);
        int   i1 = __shfl(idx_l, k + 1);
        int   i2 = __shfl(idx_l, k + 2);
        int   i3 = __shfl(idx_l, k + 3);
        float w0 = __shfl(w_l, k + 0);
        float w1 = __shfl(w_l, k + 1);
        float w2 = __shfl(w_l, k + 2);
        float w3 = __shfl(w_l, k + 3);
        // 4 independent 128B coalesced bf16 gathers in flight
        float v0 = __bfloat162float(xT[(size_t)i0 * 64 + lane]);
        float v1 = __bfloat162float(xT[(size_t)i1 * 64 + lane]);
        float v2 = __bfloat162float(xT[(size_t)i2 * 64 + lane]);
        float v3 = __bfloat162float(xT[(size_t)i3 * 64 + lane]);
        acc = fmaf(v0, w0, acc);
        acc = fmaf(v1, w1, acc);
        acc = fmaf(v2, w2, acc);
        acc = fmaf(v3, w3, acc);
    }
    outT[(size_t)g * 64 + lane] = acc + bias[g];
}

// ---------- fallback (ws too small): direct, slow but correct ----------
__global__ __launch_bounds__(256) void direct_kernel(
    const float* __restrict__ x, const float* __restrict__ kern,
    const float* __restrict__ bias, const int* __restrict__ gidx,
    const int* __restrict__ lengths, float* __restrict__ out) {
    const int wave = threadIdx.x >> 6;
    const int lane = threadIdx.x & 63;   // batch
    const int g = blockIdx.x * 4 + wave;
    if (g >= N_OUT) return;
    const int len = lengths[g];
    float acc = 0.0f;
    for (int k = 0; k < len; ++k) {
        int   idx = gidx[g * KMAX + k];
        float w   = kern[k * N_OUT + g];
        acc = fmaf(x[(size_t)lane * N_IN + idx], w, acc);
    }
    out[(size_t)lane * N_OUT + g] = acc + bias[g];
}

extern "C" void kernel_launch(void* const* d_in, const int* in_sizes, int n_in,
                              void* d_out, int out_size, void* d_ws, size_t ws_size,
                              hipStream_t stream) {
    const float* x       = (const float*)d_in[0];
    const float* kern    = (const float*)d_in[1];
    const float* bias    = (const float*)d_in[2];
    const int*   gidx    = (const int*)d_in[3];
    const int*   lengths = (const int*)d_in[4];
    float*       out     = (float*)d_out;

    const size_t xT_bytes = (size_t)N_IN * B_DIM * sizeof(__hip_bfloat16); // 128 MB
    const size_t wT_bytes = (size_t)N_OUT * KMAX * sizeof(float);          // 5.12 MB
    const size_t oT_bytes = (size_t)N_OUT * B_DIM * sizeof(float);         // 5.12 MB

    if (ws_size >= xT_bytes + wT_bytes + oT_bytes) {
        __hip_bfloat16* xT = (__hip_bfloat16*)d_ws;
        float* wT = (float*)((char*)d_ws + xT_bytes);
        float* oT = (float*)((char*)d_ws + xT_bytes + wT_bytes);

        transpose_64xC_bf16<<<N_IN / 64, 256, 0, stream>>>(x, xT, N_IN);
        transpose_64xC_f32<<<(N_OUT + 63) / 64, 256, 0, stream>>>(kern, wT, N_OUT);
        gather_dot<<<N_OUT / 4, 256, 0, stream>>>(xT, wT, gidx, lengths, bias, oT);
        transpose_Cx64<<<(N_OUT + 63) / 64, 256, 0, stream>>>(oT, out, N_OUT);
    } else {
        direct_kernel<<<N_OUT / 4, 256, 0, stream>>>(x, kern, bias, gidx, lengths, out);
    }
}

// Round 4
// 103.882 us; speedup vs baseline: 1.3805x; 1.0872x over previous
//
#include <hip/hip_runtime.h>
#include <hip/hip_bf16.h>

#define B_DIM 64
#define N_IN 1000000
#define N_OUT 20000
#define KMAX 64
#define GPB 16   // groups per gather block

// ---------- zero the row-usage flags (N_IN bytes = 62500 uint4) ----------
__global__ __launch_bounds__(256) void zero_flags(uint4* __restrict__ f) {
    int tid = blockIdx.x * 256 + threadIdx.x;
    if (tid < N_IN / 16) f[tid] = uint4{0, 0, 0, 0};
}

// ---------- mark rows of x that the gather will actually read ----------
__global__ __launch_bounds__(256) void build_flags(
    const int* __restrict__ gidx, const int* __restrict__ lengths,
    unsigned char* __restrict__ flags) {
    int tid = blockIdx.x * 256 + threadIdx.x;
    int g = tid >> 6, k = tid & 63;
    if (g < N_OUT && k < lengths[g]) flags[gidx[g * KMAX + k]] = 1;
    if (tid == 0) flags[0] = 1;   // k>=len lanes gather row 0 (weight 0)
}

// ---------- transpose + downcast + masked write: x f32(64,N_IN) -> xT bf16(N_IN,64) ----------
// float4 reads (16B/lane), bf16x2 packed writes (4B/lane), per-row skip when unused.
__global__ __launch_bounds__(256) void transpose_x_bf16_masked(
    const float* __restrict__ src, __hip_bfloat16* __restrict__ dst,
    const unsigned char* __restrict__ flags) {
    __shared__ float ldsT[64 * 65];        // ldsT[c][r], pad 65 (stride%32==1)
    __shared__ unsigned char f[64];
    const int t  = threadIdx.x;
    const int c0 = blockIdx.x * 64;
    if (t < 64) f[t] = flags[c0 + t];
    // phase 1: 16 rows x 16 float4 per iter, 4 iters = full 64x64 tile
    const int col4 = (t & 15) * 4;
    const int r0   = t >> 4;               // 0..15
#pragma unroll
    for (int i = 0; i < 4; ++i) {
        int r = r0 + 16 * i;
        float4 v = *reinterpret_cast<const float4*>(&src[(size_t)r * N_IN + c0 + col4]);
        ldsT[(col4 + 0) * 65 + r] = v.x;
        ldsT[(col4 + 1) * 65 + r] = v.y;
        ldsT[(col4 + 2) * 65 + r] = v.z;
        ldsT[(col4 + 3) * 65 + r] = v.w;
    }
    __syncthreads();
    // phase 2: each half-wave writes one 128B dst row as 32x bf16x2; skip unused rows
    const int half = t & 31;               // dword index in row
    const int cb   = t >> 5;               // 0..7
#pragma unroll
    for (int i = 0; i < 8; ++i) {
        int c = cb + 8 * i;                 // dst row (= column of x)
        if (f[c]) {
            __hip_bfloat162 h2;
            h2.x = __float2bfloat16(ldsT[c * 65 + half * 2]);
            h2.y = __float2bfloat16(ldsT[c * 65 + half * 2 + 1]);
            *reinterpret_cast<__hip_bfloat162*>(&dst[(size_t)(c0 + c) * 64 + half * 2]) = h2;
        }
    }
}

// ---------- transpose f32: kern(64, C) -> wT(C, 64) ----------
__global__ __launch_bounds__(256) void transpose_64xC_f32(
    const float* __restrict__ src, float* __restrict__ dst, int C) {
    __shared__ float lds[64 * 65];
    const int c0 = blockIdx.x * 64;
    const int t  = threadIdx.x;
    const int cq = t & 63;
    const int rq = t >> 6;
#pragma unroll
    for (int i = 0; i < 16; ++i) {
        int r = i * 4 + rq;
        int c = c0 + cq;
        if (c < C) lds[r * 65 + cq] = src[r * C + c];
    }
    __syncthreads();
#pragma unroll
    for (int i = 0; i < 16; ++i) {
        int c = i * 4 + rq;
        int r = cq;
        if (c0 + c < C) dst[(c0 + c) * 64 + r] = lds[r * 65 + c];
    }
}

// ---------- gather + masked dot + fused bias/output-transpose ----------
// 1024 threads = 16 waves; wave w owns group g0+w; lane = batch.
__global__ __launch_bounds__(1024) void gather_dot_fused(
    const __hip_bfloat16* __restrict__ xT, // (N_IN, 64) bf16
    const float* __restrict__ wT,          // (N_OUT, 64)
    const int*   __restrict__ gidx,        // (N_OUT, KMAX)
    const int*   __restrict__ lengths,     // (N_OUT,)
    const float* __restrict__ bias,        // (N_OUT,)
    float*       __restrict__ out) {       // (B_DIM, N_OUT)
    __shared__ float sm[64 * 17];          // sm[b][w], pad 17
    const int wave = threadIdx.x >> 6;     // 0..15
    const int lane = threadIdx.x & 63;     // batch
    const int g0   = blockIdx.x * GPB;
    const int g    = g0 + wave;

    const int len = lengths[g];
    // coalesced prefetch of this group's 64 indices+weights; invalid lanes -> row 0, weight 0
    const int   idx_l = (lane < len) ? gidx[g * KMAX + lane] : 0;
    const float w_l   = (lane < len) ? wT[g * KMAX + lane] : 0.0f;

    float acc = 0.0f;
    for (int k = 0; k < len; k += 4) {
        int   i0 = __shfl(idx_l, k + 0);
        int   i1 = __shfl(idx_l, k + 1);
        int   i2 = __shfl(idx_l, k + 2);
        int   i3 = __shfl(idx_l, k + 3);
        float w0 = __shfl(w_l, k + 0);
        float w1 = __shfl(w_l, k + 1);
        float w2 = __shfl(w_l, k + 2);
        float w3 = __shfl(w_l, k + 3);
        // 4 independent 128B coalesced bf16 row-gathers in flight
        float v0 = __bfloat162float(xT[(size_t)i0 * 64 + lane]);
        float v1 = __bfloat162float(xT[(size_t)i1 * 64 + lane]);
        float v2 = __bfloat162float(xT[(size_t)i2 * 64 + lane]);
        float v3 = __bfloat162float(xT[(size_t)i3 * 64 + lane]);
        acc = fmaf(v0, w0, acc);
        acc = fmaf(v1, w1, acc);
        acc = fmaf(v2, w2, acc);
        acc = fmaf(v3, w3, acc);
    }
    sm[lane * 17 + wave] = acc;            // 2-way bank alias (free)
    __syncthreads();
    // write out[b][g0..g0+15]: 64B contiguous per batch row
    const int b = threadIdx.x >> 4;        // 0..63
    const int c = threadIdx.x & 15;        // 0..15
    out[(size_t)b * N_OUT + g0 + c] = sm[b * 17 + c] + bias[g0 + c];
}

// ---------- fallback (ws too small): direct, slow but correct ----------
__global__ __launch_bounds__(256) void direct_kernel(
    const float* __restrict__ x, const float* __restrict__ kern,
    const float* __restrict__ bias, const int* __restrict__ gidx,
    const int* __restrict__ lengths, float* __restrict__ out) {
    const int wave = threadIdx.x >> 6;
    const int lane = threadIdx.x & 63;     // batch
    const int g = blockIdx.x * 4 + wave;
    if (g >= N_OUT) return;
    const int len = lengths[g];
    float acc = 0.0f;
    for (int k = 0; k < len; ++k) {
        int   idx = gidx[g * KMAX + k];
        float w   = kern[k * N_OUT + g];
        acc = fmaf(x[(size_t)lane * N_IN + idx], w, acc);
    }
    out[(size_t)lane * N_OUT + g] = acc + bias[g];
}

extern "C" void kernel_launch(void* const* d_in, const int* in_sizes, int n_in,
                              void* d_out, int out_size, void* d_ws, size_t ws_size,
                              hipStream_t stream) {
    const float* x       = (const float*)d_in[0];
    const float* kern    = (const float*)d_in[1];
    const float* bias    = (const float*)d_in[2];
    const int*   gidx    = (const int*)d_in[3];
    const int*   lengths = (const int*)d_in[4];
    float*       out     = (float*)d_out;

    const size_t xT_bytes = (size_t)N_IN * B_DIM * sizeof(__hip_bfloat16); // 128 MB
    const size_t wT_bytes = (size_t)N_OUT * KMAX * sizeof(float);          // 5.12 MB
    const size_t fl_bytes = (size_t)N_IN;                                  // 1 MB

    if (ws_size >= xT_bytes + wT_bytes + fl_bytes) {
        __hip_bfloat16* xT    = (__hip_bfloat16*)d_ws;
        float*          wT    = (float*)((char*)d_ws + xT_bytes);
        unsigned char*  flags = (unsigned char*)((char*)d_ws + xT_bytes + wT_bytes);

        zero_flags<<<(N_IN / 16 + 255) / 256, 256, 0, stream>>>((uint4*)flags);
        build_flags<<<N_OUT * KMAX / 256, 256, 0, stream>>>(gidx, lengths, flags);
        transpose_x_bf16_masked<<<N_IN / 64, 256, 0, stream>>>(x, xT, flags);
        transpose_64xC_f32<<<(N_OUT + 63) / 64, 256, 0, stream>>>(kern, wT, N_OUT);
        gather_dot_fused<<<N_OUT / GPB, 1024, 0, stream>>>(xT, wT, gidx, lengths, bias, out);
    } else {
        direct_kernel<<<N_OUT / 4, 256, 0, stream>>>(x, kern, bias, gidx, lengths, out);
    }
}

// Round 6
// 91.474 us; speedup vs baseline: 1.5677x; 1.1357x over previous
//
#include <hip/hip_runtime.h>
#include <hip/hip_bf16.h>

#define B_DIM 64
#define N_IN 1000000
#define N_OUT 20000
#define KMAX 64
#define GPB 16   // groups per gather block

__device__ __forceinline__ unsigned short f32_to_bf16_bits(float f) {
    __hip_bfloat16 b = __float2bfloat16(f);
    unsigned short s;
    __builtin_memcpy(&s, &b, sizeof(s));
    return s;
}

// ---------- fused: zero row-usage flags  +  transpose kern(64,N_OUT)->wT(N_OUT,64) ----------
#define ZERO_BLOCKS 245   // 245*256*16B = 1,003,520 B >= N_IN bytes
__global__ __launch_bounds__(256) void prep_kernel(
    uint4* __restrict__ flags4, const float* __restrict__ kern, float* __restrict__ wT) {
    if (blockIdx.x < ZERO_BLOCKS) {
        int tid = blockIdx.x * 256 + threadIdx.x;
        if (tid < N_IN / 16) flags4[tid] = uint4{0, 0, 0, 0};
        return;
    }
    // kern transpose: 64x64 LDS tile
    __shared__ float lds[64 * 65];
    const int c0 = (blockIdx.x - ZERO_BLOCKS) * 64;
    const int t  = threadIdx.x;
    const int cq = t & 63;
    const int rq = t >> 6;
#pragma unroll
    for (int i = 0; i < 16; ++i) {
        int r = i * 4 + rq;
        int c = c0 + cq;
        if (c < N_OUT) lds[r * 65 + cq] = kern[r * N_OUT + c];
    }
    __syncthreads();
#pragma unroll
    for (int i = 0; i < 16; ++i) {
        int c = i * 4 + rq;
        int r = cq;
        if (c0 + c < N_OUT) wT[(c0 + c) * 64 + r] = lds[r * 65 + c];
    }
}

// ---------- mark rows of x that the gather will actually read ----------
__global__ __launch_bounds__(256) void build_flags(
    const int* __restrict__ gidx, const int* __restrict__ lengths,
    unsigned char* __restrict__ flags) {
    int tid = blockIdx.x * 256 + threadIdx.x;
    int g = tid >> 6, k = tid & 63;
    if (g < N_OUT && k < lengths[g]) flags[gidx[g * KMAX + k]] = 1;
    if (tid == 0) flags[0] = 1;   // k>=len lanes gather row 0 (weight 0)
}

// ---------- transpose + downcast + masked write: x f32(64,N_IN) -> xT bf16(N_IN,64) ----------
// float4 reads (16B/lane); ushort4 packed stores (8B/lane, 512B/wave); per-row skip.
__global__ __launch_bounds__(256) void transpose_x_bf16_masked(
    const float* __restrict__ src, __hip_bfloat16* __restrict__ dst,
    const unsigned char* __restrict__ flags) {
    __shared__ float ldsT[64 * 65];        // ldsT[c][r]
    __shared__ unsigned char f[64];
    const int t  = threadIdx.x;
    const int c0 = blockIdx.x * 64;
    if (t < 64) f[t] = flags[c0 + t];
    // phase 1: each thread reads float4; 16 rows x 16 float4 per iter, 4 iters
    const int col4 = (t & 15) * 4;
    const int r0   = t >> 4;               // 0..15
#pragma unroll
    for (int i = 0; i < 4; ++i) {
        int r = r0 + 16 * i;
        float4 v = *reinterpret_cast<const float4*>(&src[(size_t)r * N_IN + c0 + col4]);
        ldsT[(col4 + 0) * 65 + r] = v.x;
        ldsT[(col4 + 1) * 65 + r] = v.y;
        ldsT[(col4 + 2) * 65 + r] = v.z;
        ldsT[(col4 + 3) * 65 + r] = v.w;
    }
    __syncthreads();
    // phase 2: thread packs 4 bf16 (8B); 16 threads cover one 128B dst row
    const int m = t & 15;                  // 8B chunk in row
    const int cb = t >> 4;                 // 0..15
#pragma unroll
    for (int i = 0; i < 4; ++i) {
        int c = cb + 16 * i;               // dst row (= x column)
        if (f[c]) {
            ushort4 h;
            h.x = f32_to_bf16_bits(ldsT[c * 65 + m * 4 + 0]);
            h.y = f32_to_bf16_bits(ldsT[c * 65 + m * 4 + 1]);
            h.z = f32_to_bf16_bits(ldsT[c * 65 + m * 4 + 2]);
            h.w = f32_to_bf16_bits(ldsT[c * 65 + m * 4 + 3]);
            *reinterpret_cast<ushort4*>(&dst[(size_t)(c0 + c) * 64 + m * 4]) = h;
        }
    }
}

// ---------- gather + dot, paired rows: 256B/gather-instr, 2 batches/lane ----------
__global__ __launch_bounds__(1024) void gather_dot_fused(
    const __hip_bfloat16* __restrict__ xT, // (N_IN, 64) bf16
    const float* __restrict__ wT,          // (N_OUT, 64)
    const int*   __restrict__ gidx,        // (N_OUT, KMAX)
    const int*   __restrict__ lengths,     // (N_OUT,)
    const float* __restrict__ bias,        // (N_OUT,)
    float*       __restrict__ out) {       // (B_DIM, N_OUT)
    __shared__ float sm[64 * 17];
    const int wave = threadIdx.x >> 6;     // 0..15
    const int lane = threadIdx.x & 63;
    const int half = lane >> 5;            // 0: even k, 1: odd k
    const int l    = lane & 31;            // batch pair index
    const int g0   = blockIdx.x * GPB;
    const int g    = g0 + wave;

    const int len = lengths[g];
    // coalesced prefetch; invalid lanes -> row 0 (always transposed), weight 0
    const int   idx_l = (lane < len) ? gidx[g * KMAX + lane] : 0;
    const float w_l   = (lane < len) ? wT[g * KMAX + lane] : 0.0f;

    float acc0 = 0.0f, acc1 = 0.0f;
    for (int k = 0; k < len; k += 8) {
#pragma unroll
        for (int j = 0; j < 4; ++j) {
            int   kk  = k + 2 * j + half;                 // <= 63 always
            int   row = __shfl(idx_l, kk);
            float w   = __shfl(w_l, kk);
            // halves load different rows: 2 x 128B coalesced per instruction
            unsigned int u = *reinterpret_cast<const unsigned int*>(
                &xT[(size_t)row * 64 + 2 * l]);
            float f0 = __uint_as_float(u << 16);          // batch 2l
            float f1 = __uint_as_float(u & 0xFFFF0000u);  // batch 2l+1
            acc0 = fmaf(f0, w, acc0);
            acc1 = fmaf(f1, w, acc1);
        }
    }
    // combine even-k (half 0) and odd-k (half 1) partial sums
    acc0 += __shfl_xor(acc0, 32);
    acc1 += __shfl_xor(acc1, 32);
    if (half == 0) {
        sm[(2 * l + 0) * 17 + wave] = acc0;
        sm[(2 * l + 1) * 17 + wave] = acc1;
    }
    __syncthreads();
    const int b = threadIdx.x >> 4;        // 0..63
    const int c = threadIdx.x & 15;        // 0..15
    out[(size_t)b * N_OUT + g0 + c] = sm[b * 17 + c] + bias[g0 + c];
}

// ---------- fallback (ws too small): direct, slow but correct ----------
__global__ __launch_bounds__(256) void direct_kernel(
    const float* __restrict__ x, const float* __restrict__ kern,
    const float* __restrict__ bias, const int* __restrict__ gidx,
    const int* __restrict__ lengths, float* __restrict__ out) {
    const int wave = threadIdx.x >> 6;
    const int lane = threadIdx.x & 63;     // batch
    const int g = blockIdx.x * 4 + wave;
    if (g >= N_OUT) return;
    const int len = lengths[g];
    float acc = 0.0f;
    for (int k = 0; k < len; ++k) {
        int   idx = gidx[g * KMAX + k];
        float w   = kern[k * N_OUT + g];
        acc = fmaf(x[(size_t)lane * N_IN + idx], w, acc);
    }
    out[(size_t)lane * N_OUT + g] = acc + bias[g];
}

extern "C" void kernel_launch(void* const* d_in, const int* in_sizes, int n_in,
                              void* d_out, int out_size, void* d_ws, size_t ws_size,
                              hipStream_t stream) {
    const float* x       = (const float*)d_in[0];
    const float* kern    = (const float*)d_in[1];
    const float* bias    = (const float*)d_in[2];
    const int*   gidx    = (const int*)d_in[3];
    const int*   lengths = (const int*)d_in[4];
    float*       out     = (float*)d_out;

    const size_t xT_bytes = (size_t)N_IN * B_DIM * sizeof(__hip_bfloat16); // 128 MB
    const size_t wT_bytes = (size_t)N_OUT * KMAX * sizeof(float);          // 5.12 MB
    const size_t fl_bytes = (size_t)N_IN;                                  // 1 MB

    if (ws_size >= xT_bytes + wT_bytes + fl_bytes) {
        __hip_bfloat16* xT    = (__hip_bfloat16*)d_ws;
        float*          wT    = (float*)((char*)d_ws + xT_bytes);
        unsigned char*  flags = (unsigned char*)((char*)d_ws + xT_bytes + wT_bytes);

        prep_kernel<<<ZERO_BLOCKS + (N_OUT + 63) / 64, 256, 0, stream>>>(
            (uint4*)flags, kern, wT);
        build_flags<<<N_OUT * KMAX / 256, 256, 0, stream>>>(gidx, lengths, flags);
        transpose_x_bf16_masked<<<N_IN / 64, 256, 0, stream>>>(x, xT, flags);
        gather_dot_fused<<<N_OUT / GPB, 1024, 0, stream>>>(xT, wT, gidx, lengths, bias, out);
    } else {
        direct_kernel<<<N_OUT / 4, 256, 0, stream>>>(x, kern, bias, gidx, lengths, out);
    }
}

// Round 7
// 90.181 us; speedup vs baseline: 1.5902x; 1.0143x over previous
//
#include <hip/hip_runtime.h>
#include <hip/hip_bf16.h>

#define B_DIM 64
#define N_IN 1000000
#define N_OUT 20000
#define KMAX 64
#define GPB 16        // groups per gather block
#define COLS 256      // columns per transpose tile
#define NFULL 3906    // 3906*256 = 999,936 full tiles
#define TAILC 64      // 1,000,000 - 999,936
#define FLAG_MAGIC 1
#define FB 1250       // flag blocks: 20000*64/4 idx4 / 256 thr

__device__ __forceinline__ unsigned short f32_to_bf16_bits(float f) {
    __hip_bfloat16 b = __float2bfloat16(f);
    unsigned short s;
    __builtin_memcpy(&s, &b, sizeof(s));
    return s;
}
__device__ __forceinline__ unsigned int pack_bf16x2(float lo, float hi) {
    return (unsigned int)f32_to_bf16_bits(lo) | ((unsigned int)f32_to_bf16_bits(hi) << 16);
}

// ---------- prep: mark used rows (int4 gidx) + transpose kern(64,N_OUT)->wT(N_OUT,64) ----------
__global__ __launch_bounds__(256) void prep_kernel(
    const int* __restrict__ gidx, const int* __restrict__ lengths,
    unsigned char* __restrict__ flags,
    const float* __restrict__ kern, float* __restrict__ wT) {
    if (blockIdx.x < FB) {
        int tid = blockIdx.x * 256 + threadIdx.x;   // one int4 = 4 k's
        int g  = tid >> 4;                          // 16 int4 per group
        int k4 = (tid & 15) * 4;
        int len = lengths[g];
        int4 v = *reinterpret_cast<const int4*>(&gidx[g * KMAX + k4]);
        if (k4 + 0 < len) flags[v.x] = FLAG_MAGIC;
        if (k4 + 1 < len) flags[v.y] = FLAG_MAGIC;
        if (k4 + 2 < len) flags[v.z] = FLAG_MAGIC;
        if (k4 + 3 < len) flags[v.w] = FLAG_MAGIC;
        if (tid == 0) flags[0] = FLAG_MAGIC;        // k>=len lanes gather row 0 (weight 0)
        return;
    }
    // kern transpose: 64x64 LDS tile
    __shared__ float lds[64 * 65];
    const int c0 = (blockIdx.x - FB) * 64;
    const int t  = threadIdx.x;
    const int cq = t & 63;
    const int rq = t >> 6;
#pragma unroll
    for (int i = 0; i < 16; ++i) {
        int r = i * 4 + rq;
        int c = c0 + cq;
        if (c < N_OUT) lds[r * 65 + cq] = kern[r * N_OUT + c];
    }
    __syncthreads();
#pragma unroll
    for (int i = 0; i < 16; ++i) {
        int c = i * 4 + rq;
        int r = cq;
        if (c0 + c < N_OUT) wT[(c0 + c) * 64 + r] = lds[r * 65 + c];
    }
}

// ---------- transpose + downcast + masked write: x f32(64,N_IN) -> xT bf16(N_IN,64) ----------
// 64x256 tile, 512 threads. Phase 1: each wave-instr reads ONE contiguous 1KB row
// segment (lane=col/4); converts to bf16; packs row-pairs into dword LDS writes.
// LDS layout: lt32[c*33 + r/2] holds rows (2*(r/2), 2*(r/2)+1) of column c.
// Banks: 33c+r/2 mod 32 = (c + r/2) mod 32 -> max 2-way (free).
__global__ __launch_bounds__(512) void transpose_x(
    const float* __restrict__ src, __hip_bfloat16* __restrict__ dst,
    const unsigned char* __restrict__ flags) {
    __shared__ unsigned int lt32[COLS * 33];   // 33,792 B
    __shared__ unsigned char f[COLS];
    const int t  = threadIdx.x;
    const bool full = blockIdx.x < NFULL;
    const size_t c0 = (size_t)blockIdx.x * COLS;
    const int CN = full ? COLS : TAILC;
    if (t < CN) f[t] = flags[c0 + t];

    if (full) {
        const int w = t >> 6;          // wave 0..7
        const int a = t & 63;          // lane -> 4 consecutive cols
#pragma unroll
        for (int i = 0; i < 4; ++i) {
            int r0 = i * 16 + w * 2;   // row pair
            float4 v0 = *reinterpret_cast<const float4*>(&src[(size_t)r0 * N_IN + c0 + a * 4]);
            float4 v1 = *reinterpret_cast<const float4*>(&src[(size_t)(r0 + 1) * N_IN + c0 + a * 4]);
            int c = a * 4, h = r0 >> 1;
            lt32[(c + 0) * 33 + h] = pack_bf16x2(v0.x, v1.x);
            lt32[(c + 1) * 33 + h] = pack_bf16x2(v0.y, v1.y);
            lt32[(c + 2) * 33 + h] = pack_bf16x2(v0.z, v1.z);
            lt32[(c + 3) * 33 + h] = pack_bf16x2(v0.w, v1.w);
        }
    } else {
        // tail: 64 cols. 256 active threads: c_local = t&63, row-pair set rp = t>>6.
        if (t < 256) {
            const int c = t & 63;
            const int rp = t >> 6;     // 0..3
#pragma unroll
            for (int i = 0; i < 8; ++i) {
                int r0 = i * 8 + rp * 2;
                float x0 = src[(size_t)r0 * N_IN + c0 + c];
                float x1 = src[(size_t)(r0 + 1) * N_IN + c0 + c];
                lt32[c * 33 + (r0 >> 1)] = pack_bf16x2(x0, x1);
            }
        }
    }
    __syncthreads();
    // phase 2: row c of xT = 128B = 16 lanes x 8B; skip unused rows.
    const int m  = t & 15;             // 8B chunk
    const int cb = t >> 4;             // 0..31
#pragma unroll
    for (int i = 0; i < 8; ++i) {
        int c = cb + 32 * i;
        if (c < CN && f[c] == FLAG_MAGIC) {
            uint2 u;
            u.x = lt32[c * 33 + 2 * m];
            u.y = lt32[c * 33 + 2 * m + 1];
            *reinterpret_cast<uint2*>(&dst[(c0 + c) * 64 + m * 4]) = u;
        }
    }
}

// ---------- gather + dot, paired rows: 256B/gather-instr, 2 batches/lane ----------
__global__ __launch_bounds__(1024) void gather_dot_fused(
    const __hip_bfloat16* __restrict__ xT, // (N_IN, 64) bf16
    const float* __restrict__ wT,          // (N_OUT, 64)
    const int*   __restrict__ gidx,        // (N_OUT, KMAX)
    const int*   __restrict__ lengths,     // (N_OUT,)
    const float* __restrict__ bias,        // (N_OUT,)
    float*       __restrict__ out) {       // (B_DIM, N_OUT)
    __shared__ float sm[64 * 17];
    const int wave = threadIdx.x >> 6;     // 0..15
    const int lane = threadIdx.x & 63;
    const int half = lane >> 5;            // 0: even k, 1: odd k
    const int l    = lane & 31;            // batch pair index
    const int g0   = blockIdx.x * GPB;
    const int g    = g0 + wave;

    const int len = lengths[g];
    const int   idx_l = (lane < len) ? gidx[g * KMAX + lane] : 0;
    const float w_l   = (lane < len) ? wT[g * KMAX + lane] : 0.0f;

    float acc0 = 0.0f, acc1 = 0.0f;
    for (int k = 0; k < len; k += 8) {
#pragma unroll
        for (int j = 0; j < 4; ++j) {
            int   kk  = k + 2 * j + half;
            int   row = __shfl(idx_l, kk);
            float w   = __shfl(w_l, kk);
            unsigned int u = *reinterpret_cast<const unsigned int*>(
                &xT[(size_t)row * 64 + 2 * l]);
            float f0 = __uint_as_float(u << 16);
            float f1 = __uint_as_float(u & 0xFFFF0000u);
            acc0 = fmaf(f0, w, acc0);
            acc1 = fmaf(f1, w, acc1);
        }
    }
    acc0 += __shfl_xor(acc0, 32);
    acc1 += __shfl_xor(acc1, 32);
    if (half == 0) {
        sm[(2 * l + 0) * 17 + wave] = acc0;
        sm[(2 * l + 1) * 17 + wave] = acc1;
    }
    __syncthreads();
    const int b = threadIdx.x >> 4;
    const int c = threadIdx.x & 15;
    out[(size_t)b * N_OUT + g0 + c] = sm[b * 17 + c] + bias[g0 + c];
}

// ---------- fallback (ws too small): direct, slow but correct ----------
__global__ __launch_bounds__(256) void direct_kernel(
    const float* __restrict__ x, const float* __restrict__ kern,
    const float* __restrict__ bias, const int* __restrict__ gidx,
    const int* __restrict__ lengths, float* __restrict__ out) {
    const int wave = threadIdx.x >> 6;
    const int lane = threadIdx.x & 63;
    const int g = blockIdx.x * 4 + wave;
    if (g >= N_OUT) return;
    const int len = lengths[g];
    float acc = 0.0f;
    for (int k = 0; k < len; ++k) {
        int   idx = gidx[g * KMAX + k];
        float w   = kern[k * N_OUT + g];
        acc = fmaf(x[(size_t)lane * N_IN + idx], w, acc);
    }
    out[(size_t)lane * N_OUT + g] = acc + bias[g];
}

extern "C" void kernel_launch(void* const* d_in, const int* in_sizes, int n_in,
                              void* d_out, int out_size, void* d_ws, size_t ws_size,
                              hipStream_t stream) {
    const float* x       = (const float*)d_in[0];
    const float* kern    = (const float*)d_in[1];
    const float* bias    = (const float*)d_in[2];
    const int*   gidx    = (const int*)d_in[3];
    const int*   lengths = (const int*)d_in[4];
    float*       out     = (float*)d_out;

    const size_t xT_bytes = (size_t)N_IN * B_DIM * sizeof(__hip_bfloat16); // 128 MB
    const size_t wT_bytes = (size_t)N_OUT * KMAX * sizeof(float);          // 5.12 MB
    const size_t fl_bytes = (size_t)N_IN;                                  // 1 MB

    if (ws_size >= xT_bytes + wT_bytes + fl_bytes) {
        __hip_bfloat16* xT    = (__hip_bfloat16*)d_ws;
        float*          wT    = (float*)((char*)d_ws + xT_bytes);
        unsigned char*  flags = (unsigned char*)((char*)d_ws + xT_bytes + wT_bytes);

        prep_kernel<<<FB + (N_OUT + 63) / 64, 256, 0, stream>>>(
            gidx, lengths, flags, kern, wT);
        transpose_x<<<NFULL + 1, 512, 0, stream>>>(x, xT, flags);
        gather_dot_fused<<<N_OUT / GPB, 1024, 0, stream>>>(xT, wT, gidx, lengths, bias, out);
    } else {
        direct_kernel<<<N_OUT / 4, 256, 0, stream>>>(x, kern, bias, gidx, lengths, out);
    }
}